// Round 8
// baseline (223.615 us; speedup 1.0000x reference)
//
#include <hip/hip_runtime.h>
#include <stdint.h>
#include <math.h>

#define SEQ 4096
#define DM  1024
#define NH  16
#define DH  64
#define PSTR 72
#define LOG2E 1.44269504088896341f

typedef short bf16x8 __attribute__((ext_vector_type(8)));
typedef short bf16x4 __attribute__((ext_vector_type(4)));
typedef float f32x4  __attribute__((ext_vector_type(4)));

typedef const __attribute__((address_space(1))) short* gptr_t;
typedef __attribute__((address_space(3))) short* lptr_t;

__device__ __forceinline__ short f2bf(float f) {
    union { float f; uint32_t u; } x; x.f = f;
    uint32_t r = (x.u + 0x7fffu + ((x.u >> 16) & 1u)) >> 16;
    return (short)r;
}
__device__ __forceinline__ uint32_t fbits(float f) {
    union { float f; uint32_t u; } x; x.f = f; return x.u;
}

__device__ __forceinline__ void load_lds16(const short* g, const short* l) {
    __builtin_amdgcn_global_load_lds((gptr_t)(uintptr_t)g,
                                     (lptr_t)(uint32_t)(uintptr_t)l, 16, 0, 0);
}

// ---- fused prep: blocks [0,2048) convert x fp32->bf16; blocks [2048,2816)
//      transpose w [1024][3072] -> wtb [3072][1024] bf16, Q cols pre-scaled ----
__global__ __launch_bounds__(256) void cvt_fused(const float* __restrict__ x,
                                                 const float* __restrict__ w,
                                                 short* __restrict__ xb,
                                                 short* __restrict__ wtb) {
    __shared__ float T[64][69];
    const int b = blockIdx.x;
    if (b < 2048) {
        const int i = (b * 256 + threadIdx.x) * 8;
        float4 a0 = ((const float4*)(x + i))[0];
        float4 a1 = ((const float4*)(x + i))[1];
        bf16x8 p;
        p[0]=f2bf(a0.x); p[1]=f2bf(a0.y); p[2]=f2bf(a0.z); p[3]=f2bf(a0.w);
        p[4]=f2bf(a1.x); p[5]=f2bf(a1.y); p[6]=f2bf(a1.z); p[7]=f2bf(a1.w);
        *(bf16x8*)(xb + i) = p;
        return;
    }
    const int bb = b - 2048;
    const int n0 = (bb % 48) * 64, k0 = (bb / 48) * 64;
    const int t = threadIdx.x;
    {
        const int kr = t >> 4, nc = (t & 15) * 4;
        #pragma unroll
        for (int i = 0; i < 4; ++i) {
            float4 v = *(const float4*)(w + (size_t)(k0 + kr + i * 16) * 3072 + n0 + nc);
            T[kr + i * 16][nc + 0] = v.x; T[kr + i * 16][nc + 1] = v.y;
            T[kr + i * 16][nc + 2] = v.z; T[kr + i * 16][nc + 3] = v.w;
        }
    }
    __syncthreads();
    const int nr = t >> 4, kc = (t & 15) * 4;
    #pragma unroll
    for (int i = 0; i < 4; ++i) {
        const int n = n0 + nr + i * 16;
        const float sc = (n >= 1024 && n < 2048) ? (LOG2E / 32.0f) : 1.0f;
        short4 o;
        o.x = f2bf(T[kc + 0][nr + i * 16] * sc);
        o.y = f2bf(T[kc + 1][nr + i * 16] * sc);
        o.z = f2bf(T[kc + 2][nr + i * 16] * sc);
        o.w = f2bf(T[kc + 3][nr + i * 16] * sc);
        *(short4*)(wtb + (size_t)n * 1024 + k0 + kc) = o;
    }
}

// ---- QKV GEMM (m97 structure): 128x128 tile, BK=64, global_load_lds ----
__global__ __launch_bounds__(256) void qkv_gemm(const short* __restrict__ xb,
                                                const short* __restrict__ wtb,
                                                short* __restrict__ kq,
                                                short* __restrict__ vt) {
    __shared__ short As[128 * 64];
    __shared__ short Bs[128 * 64];
    const int col0 = blockIdx.y * 128, row0 = blockIdx.x * 128;
    const int tid = threadIdx.x, w = tid >> 6, lane = tid & 63;
    const int lmod = lane & 15, ldiv = lane >> 4;
    const int wr = (w >> 1) * 64, wc = (w & 1) * 64;

    f32x4 acc[4][4] = {};
    const short* Ag = xb  + (size_t)row0 * DM;
    const short* Bg = wtb + (size_t)col0 * DM;

    for (int k0 = 0; k0 < DM; k0 += 64) {
        __syncthreads();
        #pragma unroll
        for (int t = 0; t < 4; ++t) {
            const int o = (w * 4 + t) * 1024 + lane * 16;
            const int r = o >> 7, cs = (o & 127) >> 1;
            load_lds16(Ag + (size_t)r * DM + k0 + cs, As + (w * 4 + t) * 512);
            load_lds16(Bg + (size_t)r * DM + k0 + cs, Bs + (w * 4 + t) * 512);
        }
        __syncthreads();
        #pragma unroll
        for (int ks = 0; ks < 2; ++ks) {
            bf16x8 af[4], bf[4];
            #pragma unroll
            for (int i = 0; i < 4; ++i)
                af[i] = *(const bf16x8*)(As + (wr + i * 16 + lmod) * 64 + ks * 32 + ldiv * 8);
            #pragma unroll
            for (int j = 0; j < 4; ++j)
                bf[j] = *(const bf16x8*)(Bs + (wc + j * 16 + lmod) * 64 + ks * 32 + ldiv * 8);
            #pragma unroll
            for (int i = 0; i < 4; ++i)
                #pragma unroll
                for (int j = 0; j < 4; ++j)
                    acc[i][j] = __builtin_amdgcn_mfma_f32_16x16x32_bf16(af[i], bf[j], acc[i][j], 0, 0, 0);
        }
    }

    if (col0 < 2048) {
        #pragma unroll
        for (int i = 0; i < 4; ++i)
            #pragma unroll
            for (int j = 0; j < 4; ++j)
                #pragma unroll
                for (int r = 0; r < 4; ++r)
                    kq[(size_t)(row0 + wr + i * 16 + ldiv * 4 + r) * 2048
                       + col0 + wc + j * 16 + lmod] = f2bf(acc[i][j][r]);
    } else {
        #pragma unroll
        for (int i = 0; i < 4; ++i) {
            const int ig = row0 + wr + i * 16 + ldiv * 4;
            #pragma unroll
            for (int j = 0; j < 4; ++j) {
                const int cg = col0 + wc + j * 16 + lmod - 2048;
                const int h = cg >> 6, d = cg & 63;
                bf16x4 p;
                p[0]=f2bf(acc[i][j][0]); p[1]=f2bf(acc[i][j][1]);
                p[2]=f2bf(acc[i][j][2]); p[3]=f2bf(acc[i][j][3]);
                *(bf16x4*)(vt + (size_t)(h * 64 + d) * SEQ + ig) = p;
            }
        }
    }
}

// ---- flash attention, split-K 4-way with atomic accumulation.
//      S^T = K.Q^T (swapped MFMA operands): C-layout gives each lane 4
//      consecutive j -> packed b64 P-writes, per-lane lsum over regs.
//      Fixed-max exp2 softmax; 2048 blocks (8/CU queued) for backfill. ----
__global__ __launch_bounds__(256, 4) void attn(const short* __restrict__ kq,
                                               const short* __restrict__ vt,
                                               float* __restrict__ oacc,
                                               float* __restrict__ ls) {
    __shared__ short Ks[64 * 64];
    __shared__ short Vs[64 * 64];
    __shared__ short Ps[4 * 32 * PSTR];

    const int b = blockIdx.x;
    const int qt = 31 - (b >> 6);            // LPT: big chunks first
    const int h = (b >> 2) & 15, s = b & 3;
    const int T = 2 * qt + 2;
    const int c0 = (s * T) >> 2, c1 = ((s + 1) * T) >> 2;
    if (c0 == c1) return;                    // empty chunk (uniform exit)

    const int tid = threadIdx.x, w = tid >> 6, lane = tid & 63;
    const int lmod = lane & 15, ldiv = lane >> 4;
    const float slope2 = exp2f(-0.5f * (float)(h + 1)) * LOG2E;

    // staging (wave w -> rows w*16..+15), XOR swizzle on global source chunk
    const int sr0 = w * 16 + (lane >> 3), sr1 = sr0 + 8;
    const int sc0 = (lane & 7) ^ (sr0 & 7), sc1 = (lane & 7) ^ (sr1 & 7);
    const int xorm = lmod & 7;
    const int cx0 = ldiv ^ xorm, cx1 = (4 + ldiv) ^ xorm;

    const int rowbase = qt * 128 + w * 32;
    short* pw = Ps + w * 32 * PSTR;

    // Q fragments (B-operand; same lane mapping as A)
    bf16x8 qf[2][2];
    #pragma unroll
    for (int m = 0; m < 2; ++m) {
        const short* qp = kq + (size_t)(rowbase + m * 16 + lmod) * 2048 + 1024 + h * 64;
        qf[m][0] = *(const bf16x8*)(qp + ldiv * 8);
        qf[m][1] = *(const bf16x8*)(qp + 32 + ldiv * 8);
    }
    // j - i = kt*64 + jb*16 + r + dbI[ib]
    int dbI[2];
    float pre[2][4];
    #pragma unroll
    for (int ib = 0; ib < 2; ++ib) {
        dbI[ib] = ldiv * 4 - rowbase - ib * 16 - lmod;
        #pragma unroll
        for (int r = 0; r < 4; ++r) pre[ib][r] = slope2 * (float)(dbI[ib] + r);
    }

    f32x4 O[2][4] = {};
    float lsum[2] = {0.f, 0.f};

    for (int kt = c0; kt < c1; ++kt) {
        __syncthreads();
        {
            const short* kb = kq + (size_t)(kt * 64) * 2048 + h * 64;
            load_lds16(kb + (size_t)sr0 * 2048 + sc0 * 8, Ks + (w * 16) * 64);
            load_lds16(kb + (size_t)sr1 * 2048 + sc1 * 8, Ks + (w * 16 + 8) * 64);
            const short* vb = vt + (size_t)(h * 64) * SEQ + kt * 64;
            load_lds16(vb + (size_t)sr0 * SEQ + sc0 * 8, Vs + (w * 16) * 64);
            load_lds16(vb + (size_t)sr1 * SEQ + sc1 * 8, Vs + (w * 16 + 8) * 64);
        }
        __syncthreads();

        const bool diag = (kt >= 2 * qt);
        const int dt = kt * 64;

        // S^T blocks, jb-outer (j rows in regs, i in lanes)
        #pragma unroll
        for (int jb = 0; jb < 4; ++jb) {
            const float cn = slope2 * (float)(dt + jb * 16);
            f32x4 sc[2];
            #pragma unroll
            for (int ib = 0; ib < 2; ++ib)
                #pragma unroll
                for (int r = 0; r < 4; ++r) sc[ib][r] = pre[ib][r] + cn;
            #pragma unroll
            for (int ks = 0; ks < 2; ++ks) {
                bf16x8 kf = *(const bf16x8*)(Ks + (jb * 16 + lmod) * 64 + ((ks ? cx1 : cx0) << 3));
                #pragma unroll
                for (int ib = 0; ib < 2; ++ib)
                    sc[ib] = __builtin_amdgcn_mfma_f32_16x16x32_bf16(kf, qf[ib][ks], sc[ib], 0, 0, 0);
            }
            #pragma unroll
            for (int ib = 0; ib < 2; ++ib) {
                float p0, p1, p2, p3;
                if (diag) {
                    const int dj = dt + jb * 16 + dbI[ib];
                    p0 = __builtin_amdgcn_exp2f((dj + 0 > 0) ? -1e30f : sc[ib][0]);
                    p1 = __builtin_amdgcn_exp2f((dj + 1 > 0) ? -1e30f : sc[ib][1]);
                    p2 = __builtin_amdgcn_exp2f((dj + 2 > 0) ? -1e30f : sc[ib][2]);
                    p3 = __builtin_amdgcn_exp2f((dj + 3 > 0) ? -1e30f : sc[ib][3]);
                } else {
                    p0 = __builtin_amdgcn_exp2f(sc[ib][0]);
                    p1 = __builtin_amdgcn_exp2f(sc[ib][1]);
                    p2 = __builtin_amdgcn_exp2f(sc[ib][2]);
                    p3 = __builtin_amdgcn_exp2f(sc[ib][3]);
                }
                lsum[ib] += (p0 + p1) + (p2 + p3);
                uint2 pk;
                pk.x = (fbits(p0) >> 16) | (fbits(p1) & 0xFFFF0000u);
                pk.y = (fbits(p2) >> 16) | (fbits(p3) & 0xFFFF0000u);
                *(uint2*)(pw + (ib * 16 + lmod) * PSTR + jb * 16 + ldiv * 4) = pk;
            }
        }

        // P A-frags: same-wave LDS RAW (lgkmcnt ordering, no barrier)
        bf16x8 pa[2][2];
        #pragma unroll
        for (int ib = 0; ib < 2; ++ib) {
            pa[ib][0] = *(const bf16x8*)(pw + (ib * 16 + lmod) * PSTR + ldiv * 8);
            pa[ib][1] = *(const bf16x8*)(pw + (ib * 16 + lmod) * PSTR + 32 + ldiv * 8);
        }
        #pragma unroll
        for (int ks = 0; ks < 2; ++ks) {
            const int cxo = (ks ? cx1 : cx0) << 3;
            #pragma unroll
            for (int nt = 0; nt < 4; ++nt) {
                bf16x8 vf = *(const bf16x8*)(Vs + (nt * 16 + lmod) * 64 + cxo);
                #pragma unroll
                for (int ib = 0; ib < 2; ++ib)
                    O[ib][nt] = __builtin_amdgcn_mfma_f32_16x16x32_bf16(pa[ib][ks], vf, O[ib][nt], 0, 0, 0);
            }
        }
    }

    // lsum: reduce across quads (lanes with same lmod)
    #pragma unroll
    for (int ib = 0; ib < 2; ++ib) {
        float v = lsum[ib];
        v += __shfl_xor(v, 16);
        v += __shfl_xor(v, 32);
        lsum[ib] = v;
    }
    if (ldiv == 0) {
        #pragma unroll
        for (int ib = 0; ib < 2; ++ib)
            unsafeAtomicAdd(&ls[h * SEQ + rowbase + ib * 16 + lmod], lsum[ib]);
    }
    #pragma unroll
    for (int ib = 0; ib < 2; ++ib) {
        const int i0 = rowbase + ib * 16 + ldiv * 4;
        #pragma unroll
        for (int nt = 0; nt < 4; ++nt)
            #pragma unroll
            for (int r = 0; r < 4; ++r)
                unsafeAtomicAdd(&oacc[(size_t)(i0 + r) * DM + h * 64 + nt * 16 + lmod],
                                O[ib][nt][r]);
    }
}

// ---- combine: out = Oacc / ls ----
__global__ __launch_bounds__(256) void combine(float* __restrict__ out,
                                               const float* __restrict__ oacc,
                                               const float* __restrict__ ls) {
    const int i8 = (blockIdx.x * 256 + threadIdx.x) * 8;
    const int row = i8 >> 10, col = i8 & 1023, h = col >> 6;
    const float rc = 1.0f / ls[h * SEQ + row];
    float4 a0 = *(const float4*)(oacc + i8);
    float4 a1 = *(const float4*)(oacc + i8 + 4);
    float4 c0, c1;
    c0.x = a0.x * rc; c0.y = a0.y * rc; c0.z = a0.z * rc; c0.w = a0.w * rc;
    c1.x = a1.x * rc; c1.y = a1.y * rc; c1.z = a1.z * rc; c1.w = a1.w * rc;
    *(float4*)(out + i8) = c0;
    *(float4*)(out + i8 + 4) = c1;
}

extern "C" void kernel_launch(void* const* d_in, const int* in_sizes, int n_in,
                              void* d_out, int out_size, void* d_ws, size_t ws_size,
                              hipStream_t stream) {
    const float* x = (const float*)d_in[0];   // [1,4096,1024] fp32
    const float* w = (const float*)d_in[1];   // [1024,3072] fp32
    float* out = (float*)d_out;

    char* ws = (char*)d_ws;
    short* kq   = (short*)(ws);                        // 16 MB: K|Q [4096][2048]
    short* vt   = (short*)(ws + ((size_t)16 << 20));   //  8 MB: V^T [16][64][4096]
    short* xb   = (short*)(ws + ((size_t)24 << 20));   //  8 MB: x bf16 (dead after gemm)
    short* wtb  = (short*)(ws + ((size_t)32 << 20));   //  6 MB: w^T bf16 (dead after gemm)
    float* oacc = (float*)(ws + ((size_t)24 << 20));   // 16 MB: O accumulator (reuses xb/wtb)
    float* ls   = (float*)(ws + ((size_t)40 << 20));   // 256 KB: lsum accumulator

    cvt_fused<<<2048 + 768, 256, 0, stream>>>(x, w, xb, wtb);
    qkv_gemm <<<dim3(SEQ / 128, 3072 / 128), 256, 0, stream>>>(xb, wtb, kq, vt);
    hipMemsetAsync(ws + ((size_t)24 << 20), 0, ((size_t)16 << 20) + (256 << 10), stream);
    attn     <<<2048, 256, 0, stream>>>(kq, vt, oacc, ls);
    combine  <<<SEQ * DM / (256 * 8), 256, 0, stream>>>(out, oacc, ls);
}

// Round 9
// 197.009 us; speedup vs baseline: 1.1350x; 1.1350x over previous
//
#include <hip/hip_runtime.h>
#include <stdint.h>
#include <math.h>

#define SEQ 4096
#define DM  1024
#define NH  16
#define DH  64
#define PPAD 72
#define LOG2E 1.44269504088896341f

typedef short bf16x8 __attribute__((ext_vector_type(8)));
typedef short bf16x4 __attribute__((ext_vector_type(4)));
typedef float f32x4  __attribute__((ext_vector_type(4)));

typedef const __attribute__((address_space(1))) short* gptr_t;
typedef __attribute__((address_space(3))) short* lptr_t;

__device__ __forceinline__ short f2bf(float f) {
    union { float f; uint32_t u; } x; x.f = f;
    uint32_t r = (x.u + 0x7fffu + ((x.u >> 16) & 1u)) >> 16;
    return (short)r;
}
__device__ __forceinline__ short f2bf_trunc(float f) {
    union { float f; uint32_t u; } x; x.f = f;
    return (short)(x.u >> 16);
}
__device__ __forceinline__ float bf2f(short s) {
    union { uint32_t u; float f; } x; x.u = ((uint32_t)(uint16_t)s) << 16;
    return x.f;
}

__device__ __forceinline__ void load_lds16(const short* g, const short* l) {
    __builtin_amdgcn_global_load_lds((gptr_t)(uintptr_t)g,
                                     (lptr_t)(uint32_t)(uintptr_t)l, 16, 0, 0);
}

// ---- fused prep: blocks [0,2048) convert x fp32->bf16; blocks [2048,2816)
//      transpose w [1024][3072] -> wtb [3072][1024] bf16, Q cols pre-scaled ----
__global__ __launch_bounds__(256) void cvt_fused(const float* __restrict__ x,
                                                 const float* __restrict__ w,
                                                 short* __restrict__ xb,
                                                 short* __restrict__ wtb) {
    __shared__ float T[64][69];
    const int b = blockIdx.x;
    if (b < 2048) {
        const int i = (b * 256 + threadIdx.x) * 8;
        float4 a0 = ((const float4*)(x + i))[0];
        float4 a1 = ((const float4*)(x + i))[1];
        bf16x8 p;
        p[0]=f2bf(a0.x); p[1]=f2bf(a0.y); p[2]=f2bf(a0.z); p[3]=f2bf(a0.w);
        p[4]=f2bf(a1.x); p[5]=f2bf(a1.y); p[6]=f2bf(a1.z); p[7]=f2bf(a1.w);
        *(bf16x8*)(xb + i) = p;
        return;
    }
    const int bb = b - 2048;
    const int n0 = (bb % 48) * 64, k0 = (bb / 48) * 64;
    const int t = threadIdx.x;
    {
        const int kr = t >> 4, nc = (t & 15) * 4;
        #pragma unroll
        for (int i = 0; i < 4; ++i) {
            float4 v = *(const float4*)(w + (size_t)(k0 + kr + i * 16) * 3072 + n0 + nc);
            T[kr + i * 16][nc + 0] = v.x; T[kr + i * 16][nc + 1] = v.y;
            T[kr + i * 16][nc + 2] = v.z; T[kr + i * 16][nc + 3] = v.w;
        }
    }
    __syncthreads();
    const int nr = t >> 4, kc = (t & 15) * 4;
    #pragma unroll
    for (int i = 0; i < 4; ++i) {
        const int n = n0 + nr + i * 16;
        const float sc = (n >= 1024 && n < 2048) ? (LOG2E / 32.0f) : 1.0f;
        short4 o;
        o.x = f2bf(T[kc + 0][nr + i * 16] * sc);
        o.y = f2bf(T[kc + 1][nr + i * 16] * sc);
        o.z = f2bf(T[kc + 2][nr + i * 16] * sc);
        o.w = f2bf(T[kc + 3][nr + i * 16] * sc);
        *(short4*)(wtb + (size_t)n * 1024 + k0 + kc) = o;
    }
}

// ---- QKV GEMM (m97 structure): 128x128 tile, BK=64, global_load_lds ----
__global__ __launch_bounds__(256) void qkv_gemm(const short* __restrict__ xb,
                                                const short* __restrict__ wtb,
                                                short* __restrict__ kq,
                                                short* __restrict__ vt) {
    __shared__ short As[128 * 64];
    __shared__ short Bs[128 * 64];
    const int col0 = blockIdx.y * 128, row0 = blockIdx.x * 128;
    const int tid = threadIdx.x, w = tid >> 6, lane = tid & 63;
    const int lmod = lane & 15, ldiv = lane >> 4;
    const int wr = (w >> 1) * 64, wc = (w & 1) * 64;

    f32x4 acc[4][4] = {};
    const short* Ag = xb  + (size_t)row0 * DM;
    const short* Bg = wtb + (size_t)col0 * DM;

    for (int k0 = 0; k0 < DM; k0 += 64) {
        __syncthreads();
        #pragma unroll
        for (int t = 0; t < 4; ++t) {
            const int o = (w * 4 + t) * 1024 + lane * 16;
            const int r = o >> 7, cs = (o & 127) >> 1;
            load_lds16(Ag + (size_t)r * DM + k0 + cs, As + (w * 4 + t) * 512);
            load_lds16(Bg + (size_t)r * DM + k0 + cs, Bs + (w * 4 + t) * 512);
        }
        __syncthreads();
        #pragma unroll
        for (int ks = 0; ks < 2; ++ks) {
            bf16x8 af[4], bf[4];
            #pragma unroll
            for (int i = 0; i < 4; ++i)
                af[i] = *(const bf16x8*)(As + (wr + i * 16 + lmod) * 64 + ks * 32 + ldiv * 8);
            #pragma unroll
            for (int j = 0; j < 4; ++j)
                bf[j] = *(const bf16x8*)(Bs + (wc + j * 16 + lmod) * 64 + ks * 32 + ldiv * 8);
            #pragma unroll
            for (int i = 0; i < 4; ++i)
                #pragma unroll
                for (int j = 0; j < 4; ++j)
                    acc[i][j] = __builtin_amdgcn_mfma_f32_16x16x32_bf16(af[i], bf[j], acc[i][j], 0, 0, 0);
        }
    }

    if (col0 < 2048) {
        #pragma unroll
        for (int i = 0; i < 4; ++i)
            #pragma unroll
            for (int j = 0; j < 4; ++j)
                #pragma unroll
                for (int r = 0; r < 4; ++r)
                    kq[(size_t)(row0 + wr + i * 16 + ldiv * 4 + r) * 2048
                       + col0 + wc + j * 16 + lmod] = f2bf(acc[i][j][r]);
    } else {
        #pragma unroll
        for (int i = 0; i < 4; ++i) {
            const int ig = row0 + wr + i * 16 + ldiv * 4;
            #pragma unroll
            for (int j = 0; j < 4; ++j) {
                const int cg = col0 + wc + j * 16 + lmod - 2048;
                const int h = cg >> 6, d = cg & 63;
                bf16x4 p;
                p[0]=f2bf(acc[i][j][0]); p[1]=f2bf(acc[i][j][1]);
                p[2]=f2bf(acc[i][j][2]); p[3]=f2bf(acc[i][j][3]);
                *(bf16x4*)(vt + (size_t)(h * 64 + d) * SEQ + ig) = p;
            }
        }
    }
}

// ---- flash attention, split-K 3-way + complementary pairing.
//      Block b = (h, qi, s): does chunk s of qt=31-qi AND chunk s of qt=qi
//      -> uniform 21-23 tile-units/block, 768 blocks = steady 3/CU.
//      Partials: s=0 -> fp32 (d_out, unnormalized); s=1/2 -> bf16 buffers.
//      Fixed-max exp2 softmax (Q pre-scaled log2e/32), ALiBi in acc-init,
//      global_load_lds staging with XOR swizzle on global source. ----
__global__ __launch_bounds__(256, 4) void attn(const short* __restrict__ kq,
                                               const short* __restrict__ vt,
                                               float* __restrict__ o0,
                                               short* __restrict__ p1,
                                               short* __restrict__ p2,
                                               float* __restrict__ ls) {
    __shared__ short Ks[64 * 64];
    __shared__ short Vs[64 * 64];
    __shared__ short Ps[4 * 32 * PPAD];

    const int b = blockIdx.x;
    const int h = b & 15, u = b >> 4;        // u in [0,48)
    const int qi = u & 15, s = u >> 4;       // s in {0,1,2}

    const int tid = threadIdx.x, w = tid >> 6, lane = tid & 63;
    const int lmod = lane & 15, ldiv = lane >> 4;
    const float slope2 = exp2f(-0.5f * (float)(h + 1)) * LOG2E;

    // staging (wave w -> rows w*16..+15), XOR swizzle on global source chunk
    const int sr0 = w * 16 + (lane >> 3), sr1 = sr0 + 8;
    const int sc0 = (lane & 7) ^ (sr0 & 7), sc1 = (lane & 7) ^ (sr1 & 7);
    const int xorm = lmod & 7;
    const int cx0 = ldiv ^ xorm, cx1 = (4 + ldiv) ^ xorm;
    short* pw = Ps + w * 32 * PPAD;

    for (int side = 0; side < 2; ++side) {
        const int qt = side ? qi : (31 - qi);
        const int T = 2 * qt + 2;
        const int c0 = (s * T) / 3, c1 = ((s + 1) * T) / 3;
        const int rowbase = qt * 128 + w * 32;

        // Q fragments (2 m-blocks x 2 k-steps)
        bf16x8 qf[2][2];
        #pragma unroll
        for (int m = 0; m < 2; ++m) {
            const short* qp = kq + (size_t)(rowbase + m * 16 + lmod) * 2048 + 1024 + h * 64;
            qf[m][0] = *(const bf16x8*)(qp + ldiv * 8);
            qf[m][1] = *(const bf16x8*)(qp + 32 + ldiv * 8);
        }
        int db[2];
        float pre[2][4];
        #pragma unroll
        for (int m = 0; m < 2; ++m) {
            db[m] = lmod - (rowbase + m * 16 + ldiv * 4);
            #pragma unroll
            for (int r = 0; r < 4; ++r) pre[m][r] = slope2 * (float)(db[m] - r);
        }

        f32x4 O[2][4] = {};
        float lsum[2][4] = {};

        for (int kt = c0; kt < c1; ++kt) {
            __syncthreads();
            {
                const short* kb = kq + (size_t)(kt * 64) * 2048 + h * 64;
                load_lds16(kb + (size_t)sr0 * 2048 + sc0 * 8, Ks + (w * 16) * 64);
                load_lds16(kb + (size_t)sr1 * 2048 + sc1 * 8, Ks + (w * 16 + 8) * 64);
                const short* vb = vt + (size_t)(h * 64) * SEQ + kt * 64;
                load_lds16(vb + (size_t)sr0 * SEQ + sc0 * 8, Vs + (w * 16) * 64);
                load_lds16(vb + (size_t)sr1 * SEQ + sc1 * 8, Vs + (w * 16 + 8) * 64);
            }
            __syncthreads();

            const bool diag = (kt >= 2 * qt);
            const float cb = slope2 * (float)(kt * 64);
            const int dt = kt * 64;

            #pragma unroll
            for (int nt = 0; nt < 4; ++nt) {
                const float cn = cb + slope2 * (float)(nt * 16);
                f32x4 sc[2];
                #pragma unroll
                for (int m = 0; m < 2; ++m)
                    #pragma unroll
                    for (int r = 0; r < 4; ++r) sc[m][r] = pre[m][r] + cn;
                #pragma unroll
                for (int ks = 0; ks < 2; ++ks) {
                    bf16x8 kf = *(const bf16x8*)(Ks + (nt * 16 + lmod) * 64 + ((ks ? cx1 : cx0) << 3));
                    #pragma unroll
                    for (int m = 0; m < 2; ++m)
                        sc[m] = __builtin_amdgcn_mfma_f32_16x16x32_bf16(qf[m][ks], kf, sc[m], 0, 0, 0);
                }
                if (diag) {
                    #pragma unroll
                    for (int m = 0; m < 2; ++m)
                        #pragma unroll
                        for (int r = 0; r < 4; ++r) {
                            float v = sc[m][r];
                            if (dt + nt * 16 - r + db[m] > 0) v = -1e30f;
                            const float p = __builtin_amdgcn_exp2f(v);
                            lsum[m][r] += p;
                            pw[(m * 16 + ldiv * 4 + r) * PPAD + nt * 16 + lmod] = f2bf_trunc(p);
                        }
                } else {
                    #pragma unroll
                    for (int m = 0; m < 2; ++m)
                        #pragma unroll
                        for (int r = 0; r < 4; ++r) {
                            const float p = __builtin_amdgcn_exp2f(sc[m][r]);
                            lsum[m][r] += p;
                            pw[(m * 16 + ldiv * 4 + r) * PPAD + nt * 16 + lmod] = f2bf_trunc(p);
                        }
                }
            }

            // P: same-wave LDS RAW (lgkmcnt ordering, no barrier)
            bf16x8 pa[2][2];
            #pragma unroll
            for (int m = 0; m < 2; ++m) {
                pa[m][0] = *(const bf16x8*)(pw + (m * 16 + lmod) * PPAD + ldiv * 8);
                pa[m][1] = *(const bf16x8*)(pw + (m * 16 + lmod) * PPAD + 32 + ldiv * 8);
            }
            #pragma unroll
            for (int ks = 0; ks < 2; ++ks) {
                const int cxo = (ks ? cx1 : cx0) << 3;
                #pragma unroll
                for (int nt = 0; nt < 4; ++nt) {
                    bf16x8 vf = *(const bf16x8*)(Vs + (nt * 16 + lmod) * 64 + cxo);
                    #pragma unroll
                    for (int m = 0; m < 2; ++m)
                        O[m][nt] = __builtin_amdgcn_mfma_f32_16x16x32_bf16(pa[m][ks], vf, O[m][nt], 0, 0, 0);
                }
            }
        }

        // reduce row sums across 16-lane groups
        #pragma unroll
        for (int m = 0; m < 2; ++m)
            #pragma unroll
            for (int r = 0; r < 4; ++r) {
                float v = lsum[m][r];
                v += __shfl_xor(v, 1, 16);
                v += __shfl_xor(v, 2, 16);
                v += __shfl_xor(v, 4, 16);
                v += __shfl_xor(v, 8, 16);
                lsum[m][r] = v;
            }
        if (lmod == 0) {
            #pragma unroll
            for (int m = 0; m < 2; ++m)
                #pragma unroll
                for (int r = 0; r < 4; ++r)
                    ls[s * (NH * SEQ) + h * SEQ + rowbase + m * 16 + ldiv * 4 + r] = lsum[m][r];
        }
        if (s == 0) {
            #pragma unroll
            for (int m = 0; m < 2; ++m) {
                const int i0 = rowbase + m * 16 + ldiv * 4;
                #pragma unroll
                for (int nt = 0; nt < 4; ++nt)
                    #pragma unroll
                    for (int r = 0; r < 4; ++r)
                        o0[(size_t)(i0 + r) * DM + h * 64 + nt * 16 + lmod] = O[m][nt][r];
            }
        } else {
            short* pb = (s == 1) ? p1 : p2;
            #pragma unroll
            for (int m = 0; m < 2; ++m) {
                const int i0 = rowbase + m * 16 + ldiv * 4;
                #pragma unroll
                for (int nt = 0; nt < 4; ++nt)
                    #pragma unroll
                    for (int r = 0; r < 4; ++r)
                        pb[(size_t)(i0 + r) * DM + h * 64 + nt * 16 + lmod] = f2bf(O[m][nt][r]);
            }
        }
    }
}

// ---- combine: out = (O0 + O1 + O2) / (l0 + l1 + l2) ----
__global__ __launch_bounds__(256) void combine(float* __restrict__ out,
                                               const float* __restrict__ o0,
                                               const short* __restrict__ p1,
                                               const short* __restrict__ p2,
                                               const float* __restrict__ ls) {
    const int i8 = (blockIdx.x * 256 + threadIdx.x) * 8;
    const int row = i8 >> 10, h = (i8 & 1023) >> 6;
    const int li = h * SEQ + row;
    const float l = ls[li] + ls[NH * SEQ + li] + ls[2 * NH * SEQ + li];
    const float rc = 1.0f / l;
    float4 a0 = *(const float4*)(o0 + i8);
    float4 a1 = *(const float4*)(o0 + i8 + 4);
    bf16x8 b = *(const bf16x8*)(p1 + i8);
    bf16x8 c = *(const bf16x8*)(p2 + i8);
    float4 r0, r1;
    r0.x = (a0.x + bf2f(b[0]) + bf2f(c[0])) * rc;
    r0.y = (a0.y + bf2f(b[1]) + bf2f(c[1])) * rc;
    r0.z = (a0.z + bf2f(b[2]) + bf2f(c[2])) * rc;
    r0.w = (a0.w + bf2f(b[3]) + bf2f(c[3])) * rc;
    r1.x = (a1.x + bf2f(b[4]) + bf2f(c[4])) * rc;
    r1.y = (a1.y + bf2f(b[5]) + bf2f(c[5])) * rc;
    r1.z = (a1.z + bf2f(b[6]) + bf2f(c[6])) * rc;
    r1.w = (a1.w + bf2f(b[7]) + bf2f(c[7])) * rc;
    *(float4*)(out + i8) = r0;
    *(float4*)(out + i8 + 4) = r1;
}

extern "C" void kernel_launch(void* const* d_in, const int* in_sizes, int n_in,
                              void* d_out, int out_size, void* d_ws, size_t ws_size,
                              hipStream_t stream) {
    const float* x = (const float*)d_in[0];   // [1,4096,1024] fp32
    const float* w = (const float*)d_in[1];   // [1024,3072] fp32
    float* out = (float*)d_out;

    char* ws = (char*)d_ws;
    short* kq  = (short*)(ws);                        // 16 MB: K|Q [4096][2048]
    short* vt  = (short*)(ws + ((size_t)16 << 20));   //  8 MB: V^T [16][64][4096]
    short* xb  = (short*)(ws + ((size_t)24 << 20));   //  8 MB: x bf16 (dead after gemm)
    short* wtb = (short*)(ws + ((size_t)32 << 20));   //  6 MB: w^T bf16 (dead after gemm)
    short* p1  = (short*)(ws + ((size_t)24 << 20));   //  8 MB: s=1 partial O bf16 (alias xb)
    short* p2  = (short*)(ws + ((size_t)32 << 20));   //  8 MB: s=2 partial O bf16 (alias wtb)
    float* ls  = (float*)(ws + ((size_t)40 << 20));   // 768 KB: lsum [3][16][4096]

    cvt_fused<<<2048 + 768, 256, 0, stream>>>(x, w, xb, wtb);
    qkv_gemm <<<dim3(SEQ / 128, 3072 / 128), 256, 0, stream>>>(xb, wtb, kq, vt);
    attn     <<<768, 256, 0, stream>>>(kq, vt, out, p1, p2, ls);
    combine  <<<SEQ * DM / (256 * 8), 256, 0, stream>>>(out, out, p1, p2, ls);
}